// Round 1
// baseline (78.671 us; speedup 1.0000x reference)
//
#include <hip/hip_runtime.h>

// LiftSplatShoot: out(B,N,3+C,H,W,D) = concat(world, feats_broadcast)
// B=4 N=6 C=80 H=16 W=44 D=59  -> out has 82,739,712 fp32 elements (~331 MB)

#define BB 4
#define NN 6
#define CC 80
#define HH 16
#define WW 44
#define DD 59
#define BN (BB*NN)          // 24
#define PP (HH*WW)          // 704
#define CHO (CC+3)          // 83
#define WD (WW*DD)          // 2596

// ws layout (floats): [bn*12 .. ] M(9)+t(3) per bn; then BN*PP d_last values
#define WS_DLAST (BN*12)

__device__ inline float waveMax(float v) {
#pragma unroll
    for (int o = 32; o; o >>= 1) v = fmaxf(v, __shfl_xor(v, o));
    return v;
}
__device__ inline float waveSum(float v) {
#pragma unroll
    for (int o = 32; o; o >>= 1) v += __shfl_xor(v, o);
    return v;
}

// One block per (b,n): softmax of channel C-1 over spatial, plus M = R*K^-1 and t.
__global__ __launch_bounds__(256) void lss_prep(const float* __restrict__ feats,
                                                const float* __restrict__ intr,
                                                const float* __restrict__ extr,
                                                float* __restrict__ ws) {
    const int bn = blockIdx.x;
    const int tid = threadIdx.x;
    float* Mt = ws + bn * 12;
    float* dlast = ws + WS_DLAST + (size_t)bn * PP;
    const float* f = feats + ((size_t)bn * CC + (CC - 1)) * PP;

    __shared__ float sred[4];
    __shared__ float s_max, s_sum;

    // --- max over 704 elems ---
    float m = -1e30f;
    for (int p = tid; p < PP; p += 256) m = fmaxf(m, f[p]);
    m = waveMax(m);
    if ((tid & 63) == 0) sred[tid >> 6] = m;
    __syncthreads();
    if (tid == 0) s_max = fmaxf(fmaxf(sred[0], sred[1]), fmaxf(sred[2], sred[3]));
    __syncthreads();
    const float mm = s_max;

    // --- sum of exp ---
    float s = 0.f;
    for (int p = tid; p < PP; p += 256) s += expf(f[p] - mm);
    s = waveSum(s);
    if ((tid & 63) == 0) sred[tid >> 6] = s;
    __syncthreads();
    if (tid == 0) s_sum = sred[0] + sred[1] + sred[2] + sred[3];
    __syncthreads();
    const float inv = 1.0f / s_sum;

    for (int p = tid; p < PP; p += 256) dlast[p] = expf(f[p] - mm) * inv;

    // --- M = R * K^-1, t ---  (single thread; trivial)
    if (tid == 0) {
        const float* K = intr + bn * 16;
        float a = K[0], b = K[1], c = K[2];
        float d = K[4], e = K[5], ff = K[6];
        float g = K[8], h = K[9], i = K[10];
        float det = a * (e * i - ff * h) - b * (d * i - ff * g) + c * (d * h - e * g);
        float id = 1.0f / det;
        float kinv[9] = {
            (e * i - ff * h) * id, (c * h - b * i) * id, (b * ff - c * e) * id,
            (ff * g - d * i) * id, (a * i - c * g) * id, (c * d - a * ff) * id,
            (d * h - e * g) * id,  (b * g - a * h) * id, (a * e - b * d) * id
        };
        const float* E = extr + bn * 16;
#pragma unroll
        for (int r = 0; r < 3; ++r) {
#pragma unroll
            for (int cc2 = 0; cc2 < 3; ++cc2) {
                float acc = 0.f;
#pragma unroll
                for (int k = 0; k < 3; ++k) acc += E[r * 4 + k] * kinv[k * 3 + cc2];
                Mt[r * 3 + cc2] = acc;
            }
            Mt[9 + r] = E[r * 4 + 3];
        }
    }
}

// One block per (bn,ch,h): write W*D = 2596 contiguous floats as 649 float4s.
__global__ __launch_bounds__(256) void lss_write(const float* __restrict__ feats,
                                                 const float* __restrict__ ws,
                                                 float* __restrict__ out) {
    const int blk = blockIdx.x;
    const int h = blk & (HH - 1);
    const int chbn = blk >> 4;           // HH == 16
    const int ch = chbn % CHO;
    const int bn = chbn / CHO;
    const int tid = threadIdx.x;

    __shared__ float valw[WW];
    __shared__ float s_t;

    const float* Mt = ws + bn * 12;
    const bool isWorld = (ch < 3);

    if (isWorld) {
        if (tid < WW) {
            const float* dlast = ws + WS_DLAST + (size_t)bn * PP + h * WW;
            float x = (float)tid, y = (float)h;
            float ray = Mt[ch * 3 + 0] * x + Mt[ch * 3 + 1] * y + Mt[ch * 3 + 2];
            valw[tid] = ray * dlast[tid];
        }
        if (tid == 0) s_t = Mt[9 + ch];
    } else {
        if (tid < WW) {
            const float* frow = feats + (((size_t)bn * CC + (ch - 3)) * HH + h) * WW;
            valw[tid] = frow[tid];
        }
        if (tid == 0) s_t = 0.f;
    }
    __syncthreads();

    const float tval = s_t;
    float4* orow = (float4*)(out + (size_t)blk * WD);

    // 649 float4 per row
    for (int q = tid; q < WD / 4; q += 256) {
        int base = q * 4;
        int w = base / DD;               // const-div -> magic mul
        int d = base - w * DD;
        float4 v;
        float* pv = &v.x;
#pragma unroll
        for (int k = 0; k < 4; ++k) {
            float val = valw[w];
            if (isWorld) val = val * (0.1f + d * (0.9f / 58.f)) + tval;
            pv[k] = val;
            if (++d == DD) { d = 0; ++w; }
        }
        orow[q] = v;
    }
}

extern "C" void kernel_launch(void* const* d_in, const int* in_sizes, int n_in,
                              void* d_out, int out_size, void* d_ws, size_t ws_size,
                              hipStream_t stream) {
    const float* feats = (const float*)d_in[0];
    const float* intr  = (const float*)d_in[1];
    const float* extr  = (const float*)d_in[2];
    float* ws  = (float*)d_ws;
    float* out = (float*)d_out;

    lss_prep<<<BN, 256, 0, stream>>>(feats, intr, extr, ws);
    lss_write<<<BN * CHO * HH, 256, 0, stream>>>(feats, ws, out);
}